// Round 1
// 101.838 us; speedup vs baseline: 1.0017x; 1.0017x over previous
//
#include <hip/hip_runtime.h>

#define NPTS 384
#define DIMS 256
#define TI 4      // i-rows per block in main kernel
#define JC 24     // j-columns per block in main kernel

// ---------------------------------------------------------------------------
// Kernel 1: Gram matrices G = E * E^T for both student and teacher (grid.z).
// 32x32 output tile per 64-thread (1-wave) block, 4x4 micro-tile per thread.
// LDS stored k-major (transposed, pad to 36 floats = 144B keeps 16B align)
// so operands are fetched as ds_read_b128: 2 reads per 16 FMA.
// ---------------------------------------------------------------------------
__global__ __launch_bounds__(64) void gram_kernel(const float* __restrict__ Es,
                                                  const float* __restrict__ Et,
                                                  float* __restrict__ Gs,
                                                  float* __restrict__ Gt) {
    const float* __restrict__ E = (blockIdx.z == 0) ? Es : Et;
    float* __restrict__ G       = (blockIdx.z == 0) ? Gs : Gt;

    __shared__ float AsT[32][36];
    __shared__ float BsT[32][36];

    const int t  = threadIdx.x;      // 0..63
    const int tx = t & 7;            // 0..7
    const int ty = t >> 3;           // 0..7
    const int i0 = blockIdx.x * 32;
    const int j0 = blockIdx.y * 32;

    float acc[4][4] = {};

    for (int k0 = 0; k0 < DIMS; k0 += 32) {
        // stage 32x32 A/B tiles, transposed into k-major LDS
#pragma unroll
        for (int m = 0; m < 4; m++) {
            const int row = ty + 8 * m;
            float va[4], vb[4];
            *(float4*)va = *(const float4*)&E[(i0 + row) * DIMS + k0 + 4 * tx];
            *(float4*)vb = *(const float4*)&E[(j0 + row) * DIMS + k0 + 4 * tx];
#pragma unroll
            for (int q = 0; q < 4; q++) {
                AsT[4 * tx + q][row] = va[q];
                BsT[4 * tx + q][row] = vb[q];
            }
        }
        __syncthreads();
#pragma unroll
        for (int k = 0; k < 32; k++) {
            float a[4], b[4];
            *(float4*)a = *(const float4*)&AsT[k][4 * ty];
            *(float4*)b = *(const float4*)&BsT[k][4 * tx];
#pragma unroll
            for (int p = 0; p < 4; p++)
#pragma unroll
                for (int q = 0; q < 4; q++)
                    acc[p][q] = fmaf(a[p], b[q], acc[p][q]);
        }
        __syncthreads();
    }

#pragma unroll
    for (int p = 0; p < 4; p++) {
        float4 v = make_float4(acc[p][0], acc[p][1], acc[p][2], acc[p][3]);
        *(float4*)&G[(i0 + 4 * ty + p) * NPTS + j0 + 4 * tx] = v;
    }
}

// ---------------------------------------------------------------------------
// Kernel 2: pack per-pair data.
//   P[i][j] = { gii_s - gs_ij,  rs_ij,  gii_t - gt_ij,  rt_ij }   (float4)
//   W[i][j] = { gs_ij, gt_ij }                                    (float2)
// r on the diagonal == 0 (masks j==i / k==i exactly, as in the reference).
// ---------------------------------------------------------------------------
__global__ void pack_kernel(const float* __restrict__ Gs, const float* __restrict__ Gt,
                            float4* __restrict__ P, float2* __restrict__ W) {
    int idx = blockIdx.x * 256 + threadIdx.x;
    if (idx >= NPTS * NPTS) return;
    int i = idx / NPTS;
    int j = idx - i * NPTS;

    float gs   = Gs[idx];
    float gt   = Gt[idx];
    float gsii = Gs[i * (NPTS + 1)];
    float gsjj = Gs[j * (NPTS + 1)];
    float gtii = Gt[i * (NPTS + 1)];
    float gtjj = Gt[j * (NPTS + 1)];

    float vs = fmaxf(gsii - 2.0f * gs + gsjj, 0.0f);
    float vt = fmaxf(gtii - 2.0f * gt + gtjj, 0.0f);
    float rs = (i == j) ? 0.0f : 1.0f / fmaxf(sqrtf(vs), 1e-12f);
    float rt = (i == j) ? 0.0f : 1.0f / fmaxf(sqrtf(vt), 1e-12f);

    P[idx] = make_float4(gsii - gs, rs, gtii - gt, rt);
    W[idx] = make_float2(gs, gt);
}

// ---------------------------------------------------------------------------
// Kernel 3: main triple-loop reduction. NO LDS staging.
// Block: TI i-rows x JC j-cols, 384 threads (thread == k).
// Per-(i,j) uniform data comes from P via uniform (scalarizable) float4
// loads; per-k data is in VGPRs; G_jk pairs are one coalesced float2 load.
// angle_ijk = r_ij * fma(r_ik, G_jk + (G_ii - G_ij), -r_ik*G_ik)
// huber(x)  = m*(x - 0.5m), m = min(|x|,1)   (branch-free, exact)
// ---------------------------------------------------------------------------
__global__ __launch_bounds__(NPTS) void rkd_angle_kernel(
        const float4* __restrict__ P, const float2* __restrict__ W,
        float* __restrict__ out) {
    const int k  = threadIdx.x;            // 0..383
    const int i0 = blockIdx.x * TI;
    const int j0 = blockIdx.y * JC;

    float rsk[TI], rtk[TI], nqs[TI], nqt[TI];
#pragma unroll
    for (int r = 0; r < TI; r++) {
        float4 pk = P[(i0 + r) * NPTS + k];   // coalesced: rs_ik, rt_ik
        float2 wk = W[(i0 + r) * NPTS + k];   // coalesced: gs_ik, gt_ik
        rsk[r] = pk.y;
        rtk[r] = pk.w;
        nqs[r] = -(pk.y * wk.x);
        nqt[r] = -(pk.w * wk.y);
    }

    float acc = 0.0f;
#pragma unroll 4
    for (int j = j0; j < j0 + JC; j++) {
        float2 w = W[j * NPTS + k];           // coalesced per-lane {gs_jk, gt_jk}
#pragma unroll
        for (int r = 0; r < TI; r++) {
            float4 pj = P[(i0 + r) * NPTS + j];  // wave-uniform -> s_load_dwordx4
            float as = pj.y * fmaf(rsk[r], w.x + pj.x, nqs[r]);
            float at = pj.w * fmaf(rtk[r], w.y + pj.z, nqt[r]);
            float d  = as - at;
            float ad = fabsf(d);                 // folds into input modifiers
            float m  = fminf(ad, 1.0f);
            acc = fmaf(m, fmaf(-0.5f, m, ad), acc);
        }
    }

    // wave reduce (64-wide)
#pragma unroll
    for (int off = 32; off > 0; off >>= 1)
        acc += __shfl_down(acc, off, 64);

    __shared__ float wsum[NPTS / 64];
    const int wid  = k >> 6;
    const int lane = k & 63;
    if (lane == 0) wsum[wid] = acc;
    __syncthreads();
    if (k == 0) {
        float s = 0.0f;
#pragma unroll
        for (int w = 0; w < NPTS / 64; w++) s += wsum[w];
        atomicAdd(out, s * (1.0f / (384.0f * 384.0f * 384.0f)));
    }
}

extern "C" void kernel_launch(void* const* d_in, const int* in_sizes, int n_in,
                              void* d_out, int out_size, void* d_ws, size_t ws_size,
                              hipStream_t stream) {
    const float* student = (const float*)d_in[0];
    const float* teacher = (const float*)d_in[1];
    float* out = (float*)d_out;

    // workspace layout (16B-aligned first):
    //   P  : NPTS*NPTS float4   (2359296 B)
    //   W  : NPTS*NPTS float2   (1179648 B)
    //   Gs : NPTS*NPTS float    ( 589824 B)
    //   Gt : NPTS*NPTS float    ( 589824 B)   total ~4.5 MiB
    float4* P  = (float4*)d_ws;
    float2* W  = (float2*)(P + NPTS * NPTS);
    float*  Gs = (float*)(W + NPTS * NPTS);
    float*  Gt = Gs + NPTS * NPTS;

    hipMemsetAsync(d_out, 0, sizeof(float), stream);

    dim3 ggrid(NPTS / 32, NPTS / 32, 2);
    gram_kernel<<<ggrid, 64, 0, stream>>>(student, teacher, Gs, Gt);

    dim3 pgrid((NPTS * NPTS + 255) / 256, 1, 1);
    pack_kernel<<<pgrid, 256, 0, stream>>>(Gs, Gt, P, W);

    dim3 mgrid(NPTS / TI, NPTS / JC, 1);
    rkd_angle_kernel<<<mgrid, NPTS, 0, stream>>>(P, W, out);
}

// Round 2
// 93.172 us; speedup vs baseline: 1.0949x; 1.0930x over previous
//
#include <hip/hip_runtime.h>

#define NPTS 384
#define DIMS 256
#define TI 6      // i-rows per block in main kernel
#define JC 24     // j-columns per block in main kernel

// ---------------------------------------------------------------------------
// Kernel A: fused Gram + diagonal + pack. grid (12,12,2): one 32x32 tile of
// one matrix (z: student/teacher) per 64-thread (1-wave) block, 4x4 micro.
// LDS k-major (transposed) so fragments come via ds_read_b128.
// While the k-loop runs, 64 "diag lanes" also accumulate ||e_i||^2 for the
// 32 i-rows (lanes 0..31, from AsT columns) and 32 j-rows (lanes 32..63,
// from BsT columns) -- so the block needs no cross-block diagonal data.
// Outputs, per matrix m:
//   Pm[i][j] = { g_ii - g_ij , r_ij }  (float2; r_ij = 1/||e_i-e_j||, 0 on diag)
//   Wm[i][j] =   g_ij                  (float)
// Block (0,0,0) also zeroes out[0], replacing the hipMemsetAsync dispatch.
// ---------------------------------------------------------------------------
__global__ __launch_bounds__(64) void gram_pack_kernel(
        const float* __restrict__ Es, const float* __restrict__ Et,
        float2* __restrict__ Ps, float2* __restrict__ Pt,
        float* __restrict__ Ws, float* __restrict__ Wt,
        float* __restrict__ out) {
    const float* __restrict__ E = (blockIdx.z == 0) ? Es : Et;
    float2* __restrict__ P      = (blockIdx.z == 0) ? Ps : Pt;
    float* __restrict__ W       = (blockIdx.z == 0) ? Ws : Wt;

    if (blockIdx.x == 0 && blockIdx.y == 0 && blockIdx.z == 0 && threadIdx.x == 0)
        out[0] = 0.0f;

    __shared__ float AsT[32][36];
    __shared__ float BsT[32][36];
    __shared__ float dA[32];
    __shared__ float dB[32];

    const int t  = threadIdx.x;      // 0..63
    const int tx = t & 7;            // 0..7
    const int ty = t >> 3;           // 0..7
    const int i0 = blockIdx.x * 32;
    const int j0 = blockIdx.y * 32;

    // this thread's diagonal entry: column e of AsT (t<32) or BsT (t>=32)
    const int e = t & 31;
    const float* dsrc = (t < 32) ? &AsT[0][e] : &BsT[0][e];   // stride 36 floats
    float dsum = 0.0f;

    float acc[4][4] = {};

    for (int k0 = 0; k0 < DIMS; k0 += 32) {
        // stage 32x32 A/B tiles, transposed into k-major LDS
#pragma unroll
        for (int m = 0; m < 4; m++) {
            const int row = ty + 8 * m;
            float va[4], vb[4];
            *(float4*)va = *(const float4*)&E[(i0 + row) * DIMS + k0 + 4 * tx];
            *(float4*)vb = *(const float4*)&E[(j0 + row) * DIMS + k0 + 4 * tx];
#pragma unroll
            for (int q = 0; q < 4; q++) {
                AsT[4 * tx + q][row] = va[q];
                BsT[4 * tx + q][row] = vb[q];
            }
        }
        __syncthreads();
#pragma unroll
        for (int k = 0; k < 32; k++) {
            float a[4], b[4];
            *(float4*)a = *(const float4*)&AsT[k][4 * ty];
            *(float4*)b = *(const float4*)&BsT[k][4 * tx];
#pragma unroll
            for (int p = 0; p < 4; p++)
#pragma unroll
                for (int q = 0; q < 4; q++)
                    acc[p][q] = fmaf(a[p], b[q], acc[p][q]);
        }
        // diagonal partial for this chunk (lane-consecutive -> conflict-free)
#pragma unroll
        for (int k = 0; k < 32; k++) {
            float v = dsrc[k * 36];
            dsum = fmaf(v, v, dsum);
        }
        __syncthreads();
    }

    if (t < 32) dA[e] = dsum; else dB[e] = dsum;
    __syncthreads();

    // pack epilogue: 4x4 outputs per thread
#pragma unroll
    for (int p = 0; p < 4; p++) {
        const int i   = i0 + 4 * ty + p;
        const float dAv = dA[4 * ty + p];
        float2 prow[4];
        float  wrow[4];
#pragma unroll
        for (int q = 0; q < 4; q++) {
            const int j   = j0 + 4 * tx + q;
            const float g   = acc[p][q];
            const float dBv = dB[4 * tx + q];
            float v = fmaxf(dAv - 2.0f * g + dBv, 0.0f);
            float r = (i == j) ? 0.0f : 1.0f / fmaxf(sqrtf(v), 1e-12f);
            prow[q] = make_float2(dAv - g, r);
            wrow[q] = g;
        }
        *(float4*)&P[i * NPTS + j0 + 4 * tx]     = make_float4(prow[0].x, prow[0].y, prow[1].x, prow[1].y);
        *(float4*)&P[i * NPTS + j0 + 4 * tx + 2] = make_float4(prow[2].x, prow[2].y, prow[3].x, prow[3].y);
        *(float4*)&W[i * NPTS + j0 + 4 * tx]     = make_float4(wrow[0], wrow[1], wrow[2], wrow[3]);
    }
}

// ---------------------------------------------------------------------------
// Kernel B: main triple-loop reduction. NO LDS staging.
// Block: TI i-rows x JC j-cols, 384 threads (thread == k), grid 64x16.
// Per-(i,j) data comes from Ps/Pt via wave-uniform (scalarizable) float2
// loads; per-k state in VGPRs; G_jk values are coalesced dword loads.
// angle_ijk = r_ij * fma(r_ik, G_jk + (G_ii - G_ij), -r_ik*G_ik)
// huber(x)  = m*(x - 0.5m), m = min(|x|,1)   (branch-free, exact)
// ---------------------------------------------------------------------------
__global__ __launch_bounds__(NPTS) void rkd_angle_kernel(
        const float2* __restrict__ Ps, const float2* __restrict__ Pt,
        const float* __restrict__ Ws, const float* __restrict__ Wt,
        float* __restrict__ out) {
    const int k  = threadIdx.x;            // 0..383
    const int i0 = blockIdx.x * TI;
    const int j0 = blockIdx.y * JC;

    float rsk[TI], rtk[TI], nqs[TI], nqt[TI];
#pragma unroll
    for (int r = 0; r < TI; r++) {
        float2 ps = Ps[(i0 + r) * NPTS + k];   // coalesced 8B
        float2 pt = Pt[(i0 + r) * NPTS + k];
        float  ws = Ws[(i0 + r) * NPTS + k];   // coalesced 4B
        float  wt = Wt[(i0 + r) * NPTS + k];
        rsk[r] = ps.y;
        rtk[r] = pt.y;
        nqs[r] = -(ps.y * ws);
        nqt[r] = -(pt.y * wt);
    }

    float acc = 0.0f;
#pragma unroll 2
    for (int j = j0; j < j0 + JC; j++) {
        float ws = Ws[j * NPTS + k];           // coalesced per-lane g_jk
        float wt = Wt[j * NPTS + k];
#pragma unroll
        for (int r = 0; r < TI; r++) {
            float2 pjs = Ps[(i0 + r) * NPTS + j];   // wave-uniform
            float2 pjt = Pt[(i0 + r) * NPTS + j];   // wave-uniform
            float as = pjs.y * fmaf(rsk[r], ws + pjs.x, nqs[r]);
            float at = pjt.y * fmaf(rtk[r], wt + pjt.x, nqt[r]);
            float d  = as - at;
            float ad = fabsf(d);
            float m  = fminf(ad, 1.0f);
            acc = fmaf(m, fmaf(-0.5f, m, ad), acc);
        }
    }

    // wave reduce (64-wide)
#pragma unroll
    for (int off = 32; off > 0; off >>= 1)
        acc += __shfl_down(acc, off, 64);

    __shared__ float wsum[NPTS / 64];
    const int wid  = k >> 6;
    const int lane = k & 63;
    if (lane == 0) wsum[wid] = acc;
    __syncthreads();
    if (k == 0) {
        float s = 0.0f;
#pragma unroll
        for (int w = 0; w < NPTS / 64; w++) s += wsum[w];
        atomicAdd(out, s * (1.0f / (384.0f * 384.0f * 384.0f)));
    }
}

extern "C" void kernel_launch(void* const* d_in, const int* in_sizes, int n_in,
                              void* d_out, int out_size, void* d_ws, size_t ws_size,
                              hipStream_t stream) {
    const float* student = (const float*)d_in[0];
    const float* teacher = (const float*)d_in[1];
    float* out = (float*)d_out;

    // workspace layout (16B-aligned blocks):
    //   Ps, Pt : NPTS*NPTS float2  (1179648 B each)
    //   Ws, Wt : NPTS*NPTS float   ( 589824 B each)   total ~3.4 MiB
    float2* Ps = (float2*)d_ws;
    float2* Pt = Ps + NPTS * NPTS;
    float*  Ws = (float*)(Pt + NPTS * NPTS);
    float*  Wt = Ws + NPTS * NPTS;

    dim3 ggrid(NPTS / 32, NPTS / 32, 2);
    gram_pack_kernel<<<ggrid, 64, 0, stream>>>(student, teacher, Ps, Pt, Ws, Wt, out);

    dim3 mgrid(NPTS / TI, NPTS / JC, 1);
    rkd_angle_kernel<<<mgrid, NPTS, 0, stream>>>(Ps, Pt, Ws, Wt, out);
}